// Round 1
// baseline (1078.797 us; speedup 1.0000x reference)
//
#include <hip/hip_runtime.h>

#define LDIM 4096
#define DDIM 64
#define KCODES 1024
#define BDIM 16
#define NROWS 65536   // BDIM * LDIM

__device__ __forceinline__ unsigned int orderf(float f) {
  unsigned int u = __float_as_uint(f);
  return (u & 0x80000000u) ? ~u : (u | 0x80000000u);
}

__device__ __forceinline__ unsigned long long shfl_xor_u64(unsigned long long v, int m) {
  int lo = __shfl_xor((int)(unsigned int)(v & 0xffffffffull), m, 64);
  int hi = __shfl_xor((int)(unsigned int)(v >> 32), m, 64);
  return ((unsigned long long)(unsigned int)hi << 32) | (unsigned int)lo;
}

// ---------------------------------------------------------------------------
// prep: per-code squared norm + softmax(E[k]) table. 1 wave per code.
// ---------------------------------------------------------------------------
__global__ void prep_kernel(const float* __restrict__ Ew,
                            float* __restrict__ enorm,
                            float* __restrict__ SE) {
  int k = blockIdx.x;
  int d = threadIdx.x;
  float v = Ew[k * DDIM + d];
  float n2 = v * v;
  #pragma unroll
  for (int o = 32; o > 0; o >>= 1) n2 += __shfl_xor(n2, o, 64);
  float m = v;
  #pragma unroll
  for (int o = 32; o > 0; o >>= 1) m = fmaxf(m, __shfl_xor(m, o, 64));
  float e = expf(v - m);
  float Z = e;
  #pragma unroll
  for (int o = 32; o > 0; o >>= 1) Z += __shfl_xor(Z, o, 64);
  SE[k * DDIM + d] = e / Z;
  if (d == 0) enorm[k] = n2;
}

// ---------------------------------------------------------------------------
// argmin: per-row nearest code. 128 rows x all 1024 codes per block.
// score = ||E_k||^2 - 2 x.E_k  (||x||^2 is row-constant, preserves order/ties)
// ---------------------------------------------------------------------------
__launch_bounds__(256, 2)
__global__ void argmin_kernel(const float* __restrict__ inp,
                              const float* __restrict__ Ew,
                              const float* __restrict__ enorm,
                              int* __restrict__ idx_ws,
                              float* __restrict__ outidx) {
  __shared__ float xs[128][68];   // +4 pad keeps float4 alignment, spreads banks
  __shared__ float es[128][68];
  __shared__ float ens[128];

  const int tid = threadIdx.x;
  const int blk = blockIdx.x;
  const int b  = blk >> 5;            // 32 blocks of 128 rows per batch
  const int l0 = (blk & 31) << 7;
  const float* xbase = inp + (size_t)b * DDIM * LDIM + l0;

  // stage x tile: xs[l][d]
  for (int i = tid; i < 128 * 64; i += 256) {
    int d = i >> 7, l = i & 127;
    xs[l][d] = xbase[d * LDIM + l];
  }

  const int tr = tid >> 4;   // 0..15 row group
  const int tc = tid & 15;   // 0..15 code group
  unsigned long long bestk[8];
  #pragma unroll
  for (int i = 0; i < 8; i++) bestk[i] = ~0ull;

  for (int chunk = 0; chunk < 8; chunk++) {
    __syncthreads();  // xs ready / previous chunk's readers done
    {
      const float4* src = (const float4*)(Ew + (size_t)chunk * 128 * 64);
      for (int j = tid; j < 2048; j += 256) {
        float4 v = src[j];
        int c = j >> 4, d4 = (j & 15) << 2;
        *(float4*)&es[c][d4] = v;
      }
      if (tid < 128) ens[tid] = enorm[chunk * 128 + tid];
    }
    __syncthreads();

    float acc[8][8];
    #pragma unroll
    for (int i = 0; i < 8; i++)
      #pragma unroll
      for (int j = 0; j < 8; j++) acc[i][j] = 0.f;

    #pragma unroll 2
    for (int k = 0; k < 64; k += 4) {
      float4 a[8], bb[8];
      #pragma unroll
      for (int i = 0; i < 8; i++) a[i] = *(const float4*)&xs[i * 16 + tr][k];
      #pragma unroll
      for (int j = 0; j < 8; j++) bb[j] = *(const float4*)&es[j * 16 + tc][k];
      #pragma unroll
      for (int i = 0; i < 8; i++) {
        #pragma unroll
        for (int j = 0; j < 8; j++) {
          acc[i][j] = fmaf(a[i].x, bb[j].x, acc[i][j]);
          acc[i][j] = fmaf(a[i].y, bb[j].y, acc[i][j]);
          acc[i][j] = fmaf(a[i].z, bb[j].z, acc[i][j]);
          acc[i][j] = fmaf(a[i].w, bb[j].w, acc[i][j]);
        }
      }
    }

    #pragma unroll
    for (int j = 0; j < 8; j++) {
      int c = j * 16 + tc;
      float en = ens[c];
      unsigned int cg = (unsigned int)(chunk * 128 + c);
      #pragma unroll
      for (int i = 0; i < 8; i++) {
        float score = fmaf(-2.f, acc[i][j], en);
        unsigned long long key = ((unsigned long long)orderf(score) << 32) | cg;
        if (key < bestk[i]) bestk[i] = key;
      }
    }
  }

  // reduce min-key across the 16 tc lanes (lane bits 0..3)
  #pragma unroll
  for (int i = 0; i < 8; i++) {
    unsigned long long k = bestk[i];
    #pragma unroll
    for (int m = 1; m < 16; m <<= 1) {
      unsigned long long o = shfl_xor_u64(k, m);
      if (o < k) k = o;
    }
    if (tc == 0) {
      int grow = blk * 128 + i * 16 + tr;
      int ci = (int)(k & 0xffffffffull);
      idx_ws[grow] = ci;
      outidx[grow] = (float)ci;
    }
  }
}

// ---------------------------------------------------------------------------
// scatter: quantized output, dw/counts accumulation, KL partial sums.
// one thread per row; lanes = consecutive l -> coalesced x reads / out writes
// ---------------------------------------------------------------------------
__launch_bounds__(256)
__global__ void scatter_kernel(const float* __restrict__ inp,
                               const float* __restrict__ Ew,
                               const float* __restrict__ SE,
                               const int* __restrict__ idx_ws,
                               float* __restrict__ out,
                               float* __restrict__ dw,
                               float* __restrict__ counts,
                               float* __restrict__ klacc) {
  int row = blockIdx.x * 256 + threadIdx.x;
  int b = row >> 12, l = row & 4095;
  const float* xp = inp + (size_t)b * DDIM * LDIM + l;
  float* op = out + (size_t)b * DDIM * LDIM + l;
  int k = idx_ws[row];

  float xr[64];
  #pragma unroll
  for (int d = 0; d < 64; d++) xr[d] = xp[d * LDIM];
  float m = xr[0];
  #pragma unroll
  for (int d = 1; d < 64; d++) m = fmaxf(m, xr[d]);

  const float* Ek = Ew + k * DDIM;
  const float* Qk = SE + k * DDIM;
  float Z = 0.f, S1 = 0.f, U = 0.f;
  #pragma unroll
  for (int d = 0; d < 64; d++) {
    float e = expf(xr[d] - m);
    Z += e;
    S1 += e * (xr[d] - m);
    U += e * Qk[d];
    op[d * LDIM] = Ek[d];
    atomicAdd(&dw[k * DDIM + d], xr[d]);
  }
  atomicAdd(&counts[k], 1.0f);

  // kl_row = sum p*(log p - q) = (S1 - U)/Z - log Z
  float kl = (S1 - U) / Z - logf(Z);
  #pragma unroll
  for (int o = 32; o > 0; o >>= 1) kl += __shfl_xor(kl, o, 64);
  if ((threadIdx.x & 63) == 0) atomicAdd(klacc, kl);
}

// ---------------------------------------------------------------------------
// finalize (small): cs normalization, loss, perplexity. 1 block x 1024.
// ---------------------------------------------------------------------------
__global__ void finalize_small(const float* __restrict__ ema_cs,
                               const float* __restrict__ counts,
                               const float* __restrict__ klacc,
                               float* __restrict__ csp,
                               float* __restrict__ loss_out,
                               float* __restrict__ perp_out) {
  __shared__ float red1[16], red2[16];
  int k = threadIdx.x;
  float cs = ema_cs[k] * 0.9f + 0.1f * counts[k];
  float n = cs;
  #pragma unroll
  for (int o = 32; o > 0; o >>= 1) n += __shfl_xor(n, o, 64);
  if ((k & 63) == 0) red1[k >> 6] = n;
  float a = counts[k] * (1.0f / 65536.0f);
  float ent = a * logf(a + 1e-10f);
  float es = ent;
  #pragma unroll
  for (int o = 32; o > 0; o >>= 1) es += __shfl_xor(es, o, 64);
  if ((k & 63) == 0) red2[k >> 6] = es;
  __syncthreads();
  if (k == 0) {
    float t1 = 0.f, t2 = 0.f;
    for (int i = 0; i < 16; i++) { t1 += red1[i]; t2 += red2[i]; }
    red1[0] = t1;
    *loss_out = 0.1f * (*klacc) * (1.0f / 16.0f);
    *perp_out = expf(-t2);
  }
  __syncthreads();
  float N = red1[0];
  csp[k] = (cs + 1e-5f) / (N + 1024.0f * 1e-5f) * N;
}

// ---------------------------------------------------------------------------
// finalize embed: new_E = (0.9*ema_w + 0.1*dw) / csp[k]
// ---------------------------------------------------------------------------
__global__ void finalize_embed(const float* __restrict__ ema_w,
                               const float* __restrict__ dw,
                               const float* __restrict__ csp,
                               float* __restrict__ emb_out) {
  int i = blockIdx.x * 256 + threadIdx.x;
  float v = fmaf(0.1f, dw[i], ema_w[i] * 0.9f);
  emb_out[i] = v / csp[i >> 6];
}

extern "C" void kernel_launch(void* const* d_in, const int* in_sizes, int n_in,
                              void* d_out, int out_size, void* d_ws, size_t ws_size,
                              hipStream_t stream) {
  const float* inp   = (const float*)d_in[0];   // (16,64,4096)
  const float* Ew    = (const float*)d_in[1];   // (1024,64)
  const float* emacs = (const float*)d_in[2];   // (1024,)
  const float* emaw  = (const float*)d_in[3];   // (1024,64)

  float* out      = (float*)d_out;              // (16,64,4096) = 4194304
  float* loss_out = out + 4194304;
  float* perp_out = out + 4194305;
  float* emb_out  = out + 4194306;              // 65536
  float* idxf_out = out + 4194306 + 65536;      // 65536 (indices as float)

  char* ws = (char*)d_ws;
  int*   idx_ws = (int*)(ws);                   // 262144 B
  float* dw     = (float*)(ws + 262144);        // 262144 B  (zeroed)
  float* counts = (float*)(ws + 524288);        // 4096 B    (zeroed)
  float* klacc  = (float*)(ws + 528384);        // 4 B       (zeroed)
  float* enorm  = (float*)(ws + 528640);        // 4096 B
  float* csp    = (float*)(ws + 532736);        // 4096 B
  float* SE     = (float*)(ws + 536832);        // 262144 B

  hipMemsetAsync(ws + 262144, 0, 262144 + 4096 + 256, stream);

  prep_kernel<<<KCODES, 64, 0, stream>>>(Ew, enorm, SE);
  argmin_kernel<<<512, 256, 0, stream>>>(inp, Ew, enorm, idx_ws, idxf_out);
  scatter_kernel<<<NROWS / 256, 256, 0, stream>>>(inp, Ew, SE, idx_ws, out, dw,
                                                  counts, klacc);
  finalize_small<<<1, 1024, 0, stream>>>(emacs, counts, klacc, csp, loss_out,
                                         perp_out);
  finalize_embed<<<256, 256, 0, stream>>>(emaw, dw, csp, emb_out);
}